// Round 10
// baseline (272.036 us; speedup 1.0000x reference)
//
#include <hip/hip_runtime.h>

#define HH 224
#define WW 224
#define K 15
#define PAD 7
#define BX 32
#define BY 8
#define TW (BX + K - 1)   /* 46 */
#define TH (BY + K - 1)   /* 22 */
#define TSTRIDE 48

#define STAGE_TILE()                                                        \
    for (int idx = tid; idx < TH * TW; idx += BX * BY) {                    \
        const int r = idx / TW;                                             \
        const int c = idx - r * TW;                                         \
        const int gh = h0 - PAD + r;                                        \
        const int gw = w0 - PAD + c;                                        \
        float v = -100.0f;                                                  \
        if (gh >= 0 && gh < HH && gw >= 0 && gw < WW) v = xp[gh * WW + gw]; \
        tile[r * TSTRIDE + c] = v;                                          \
    }                                                                       \
    __syncthreads();

/* ---------------- main kernel: exact R2 best-known, writes d_out ---------------- */
__global__ __launch_bounds__(BX * BY)
void bilateral_denoise_kernel(const float* __restrict__ x,
                              const float* __restrict__ blur_sigma_p,
                              const float* __restrict__ diff_sigma_p,
                              float* __restrict__ out)
{
    __shared__ float tile[TH * TSTRIDE];
    const int tx = threadIdx.x, ty = threadIdx.y;
    const int tid = ty * BX + tx;
    const int w0 = blockIdx.x * BX, h0 = blockIdx.y * BY;
    const int plane = blockIdx.z;
    const float* __restrict__ xp = x + (size_t)plane * HH * WW;
    STAGE_TILE()

    const float bs = blur_sigma_p[0], ds = diff_sigma_p[0];
    const float LOG2E = 1.44269504088896340736f;
    const float na  = -LOG2E / (ds * ds);
    const float nk2 = -LOG2E / (bs * bs);
    const float cv = tile[(ty + PAD) * TSTRIDE + tx + PAD];
    const float bb = -2.0f * na * cv;
    const float cc = na * cv * cv;

    float colw[K], colv[K];
#pragma unroll
    for (int j = 0; j < K; ++j) { colw[j] = 0.0f; colv[j] = 0.0f; }
#pragma unroll
    for (int i = 0; i < K; ++i) {
        const float ci = __builtin_fmaf((float)((i - PAD) * (i - PAD)), nk2, cc);
        const float* __restrict__ row = &tile[(ty + i) * TSTRIDE + tx];
#pragma unroll
        for (int j = 0; j < K; ++j) {
            const float v = row[j];
            const float inner = __builtin_fmaf(v, na, bb);
            const float t = __builtin_fmaf(v, inner, ci);
            const float e = __builtin_amdgcn_exp2f(t);
            colw[j] += e;
            colv[j] = __builtin_fmaf(e, v, colv[j]);
        }
    }
    float wsum = 0.0f, vsum = 0.0f;
#pragma unroll
    for (int j = 0; j < K; ++j) {
        const float wj = __builtin_amdgcn_exp2f((float)((j - PAD) * (j - PAD)) * nk2);
        wsum = __builtin_fmaf(wj, colw[j], wsum);
        vsum = __builtin_fmaf(wj, colv[j], vsum);
    }
    out[(size_t)plane * HH * WW + (size_t)(h0 + ty) * WW + (w0 + tx)] = vsum / wsum;
}

/* ---------------- probe 1: FULL pipeline x3 (sanity & per-rep baseline) -------- */
__global__ __launch_bounds__(BX * BY)
void probe_full(const float* __restrict__ x, const float* __restrict__ blur_sigma_p,
                const float* __restrict__ diff_sigma_p, float* __restrict__ ws,
                size_t ws_size)
{
    __shared__ float tile[TH * TSTRIDE];
    const int tx = threadIdx.x, ty = threadIdx.y;
    const int tid = ty * BX + tx;
    const int w0 = blockIdx.x * BX, h0 = blockIdx.y * BY;
    const int plane = blockIdx.z;
    const float* __restrict__ xp = x + (size_t)plane * HH * WW;
    STAGE_TILE()

    const float bs = blur_sigma_p[0], ds = diff_sigma_p[0];
    const float LOG2E = 1.44269504088896340736f;
    const float na  = -LOG2E / (ds * ds);
    const float nk2 = -LOG2E / (bs * bs);
    const float cv = tile[(ty + PAD) * TSTRIDE + tx + PAD];
    const float bb = -2.0f * na * cv;
    const float cc = na * cv * cv;

    float sink = 0.0f;
#pragma unroll 1
    for (int rep = 0; rep < 3; ++rep) {
        unsigned roff = 0;
        asm volatile("" : "+v"(roff));          // opaque: blocks load hoist/CSE
        float ccr = cc;
        asm volatile("" : "+v"(ccr));           // opaque: blocks exp2 CSE
        float colw[K], colv[K];
#pragma unroll
        for (int j = 0; j < K; ++j) { colw[j] = 0.0f; colv[j] = 0.0f; }
#pragma unroll
        for (int i = 0; i < K; ++i) {
            const float ci = __builtin_fmaf((float)((i - PAD) * (i - PAD)), nk2, ccr);
            const float* __restrict__ row = &tile[(ty + i) * TSTRIDE + tx + roff];
#pragma unroll
            for (int j = 0; j < K; ++j) {
                const float v = row[j];
                const float inner = __builtin_fmaf(v, na, bb);
                const float t = __builtin_fmaf(v, inner, ci);
                const float e = __builtin_amdgcn_exp2f(t);
                colw[j] += e;
                colv[j] = __builtin_fmaf(e, v, colv[j]);
            }
        }
        float wsum = 0.0f, vsum = 0.0f;
#pragma unroll
        for (int j = 0; j < K; ++j) {
            const float wj = __builtin_amdgcn_exp2f((float)((j - PAD) * (j - PAD)) * nk2);
            wsum = __builtin_fmaf(wj, colw[j], wsum);
            vsum = __builtin_fmaf(wj, colv[j], vsum);
        }
        sink += vsum / wsum;
    }
    const size_t gidx = (size_t)plane * HH * WW + (size_t)(h0 + ty) * WW + (w0 + tx);
    if ((gidx + 1) * sizeof(float) <= ws_size) ws[gidx] = sink;
}

/* ---------------- probe 2: LDS pipe only (read + 1 add per tap) x10 ------------ */
__global__ __launch_bounds__(BX * BY)
void probe_lds(const float* __restrict__ x, float* __restrict__ ws, size_t ws_size)
{
    __shared__ float tile[TH * TSTRIDE];
    const int tx = threadIdx.x, ty = threadIdx.y;
    const int tid = ty * BX + tx;
    const int w0 = blockIdx.x * BX, h0 = blockIdx.y * BY;
    const int plane = blockIdx.z;
    const float* __restrict__ xp = x + (size_t)plane * HH * WW;
    STAGE_TILE()

    float acc = 0.0f;
#pragma unroll 1
    for (int rep = 0; rep < 10; ++rep) {
        unsigned roff = 0;
        asm volatile("" : "+v"(roff));
#pragma unroll
        for (int i = 0; i < K; ++i) {
            const float* __restrict__ row = &tile[(ty + i) * TSTRIDE + tx + roff];
#pragma unroll
            for (int j = 0; j < K; ++j) acc += row[j];
        }
    }
    const size_t gidx = (size_t)plane * HH * WW + (size_t)(h0 + ty) * WW + (w0 + tx);
    if ((gidx + 1) * sizeof(float) <= ws_size) ws[gidx] = acc;
}

/* ---------------- probe 3: compute only (5 fma + exp2 per tap, no LDS) x10 ----- */
__global__ __launch_bounds__(BX * BY)
void probe_valu(const float* __restrict__ x, const float* __restrict__ blur_sigma_p,
                const float* __restrict__ diff_sigma_p, float* __restrict__ ws,
                size_t ws_size)
{
    const int tx = threadIdx.x, ty = threadIdx.y;
    const int w0 = blockIdx.x * BX, h0 = blockIdx.y * BY;
    const int plane = blockIdx.z;
    const size_t gidx = (size_t)plane * HH * WW + (size_t)(h0 + ty) * WW + (w0 + tx);

    const float bs = blur_sigma_p[0], ds = diff_sigma_p[0];
    const float LOG2E = 1.44269504088896340736f;
    const float na  = -LOG2E / (ds * ds);
    const float nk2 = -LOG2E / (bs * bs);
    const float cv = x[gidx];
    const float bb = -2.0f * na * cv;
    const float cc = na * cv * cv;

    float wsum = 0.0f, vsum = 0.0f;
#pragma unroll 1
    for (int rep = 0; rep < 10; ++rep) {
        float v = cv;
        asm volatile("" : "+v"(v));
#pragma unroll
        for (int i = 0; i < K; ++i) {
            const float ci = __builtin_fmaf((float)((i - PAD) * (i - PAD)), nk2, cc);
#pragma unroll
            for (int j = 0; j < K; ++j) {
                v = __builtin_fmaf(v, 1.000001f, 0.0078125f);   // evolve register value
                const float inner = __builtin_fmaf(v, na, bb);
                const float t = __builtin_fmaf(v, inner, ci);
                const float e = __builtin_amdgcn_exp2f(t);
                wsum += e;
                vsum = __builtin_fmaf(e, v, vsum);
            }
        }
    }
    if ((gidx + 1) * sizeof(float) <= ws_size) ws[gidx] = vsum / wsum;
}

/* ---------------- probe 4: trans pipe only (1 add + exp2 per tap) x12 ---------- */
__global__ __launch_bounds__(BX * BY)
void probe_trans(const float* __restrict__ x, const float* __restrict__ blur_sigma_p,
                 float* __restrict__ ws, size_t ws_size)
{
    const int tx = threadIdx.x, ty = threadIdx.y;
    const int w0 = blockIdx.x * BX, h0 = blockIdx.y * BY;
    const int plane = blockIdx.z;
    const size_t gidx = (size_t)plane * HH * WW + (size_t)(h0 + ty) * WW + (w0 + tx);

    const float bs = blur_sigma_p[0];
    const float LOG2E = 1.44269504088896340736f;
    const float nk2 = -LOG2E / (bs * bs);
    float acc = 0.0f;
    const float tb0 = x[gidx] * nk2;

#pragma unroll 1
    for (int rep = 0; rep < 12; ++rep) {
        float tb = tb0;
        asm volatile("" : "+v"(tb));
#pragma unroll
        for (int i = 0; i < K; ++i) {
#pragma unroll
            for (int j = 0; j < K; ++j) {
                const float cj = (float)((i - PAD) * (i - PAD) + (j - PAD) * (j - PAD));
                const float e = __builtin_amdgcn_exp2f(tb + cj * nk2);
                acc += e;
            }
        }
    }
    if ((gidx + 1) * sizeof(float) <= ws_size) ws[gidx] = acc;
}

extern "C" void kernel_launch(void* const* d_in, const int* in_sizes, int n_in,
                              void* d_out, int out_size, void* d_ws, size_t ws_size,
                              hipStream_t stream) {
    const float* x  = (const float*)d_in[0];
    const float* bs = (const float*)d_in[1];
    const float* ds = (const float*)d_in[2];
    float* out = (float*)d_out;
    float* ws  = (float*)d_ws;

    const int planes = in_sizes[0] / (HH * WW);   // 6
    dim3 grid(WW / BX, HH / BY, planes);          // 1176 blocks
    dim3 block(BX, BY, 1);

    // correct output first (exact R2 best-known)
    hipLaunchKernelGGL(bilateral_denoise_kernel, grid, block, 0, stream, x, bs, ds, out);
    // DIAGNOSTIC probes -> d_ws only; sized to enter rocprof top-5
    hipLaunchKernelGGL(probe_full,  grid, block, 0, stream, x, bs, ds, ws, ws_size);
    hipLaunchKernelGGL(probe_lds,   grid, block, 0, stream, x, ws, ws_size);
    hipLaunchKernelGGL(probe_valu,  grid, block, 0, stream, x, bs, ds, ws, ws_size);
    hipLaunchKernelGGL(probe_trans, grid, block, 0, stream, x, bs, ws, ws_size);
}